// Round 3
// baseline (298.213 us; speedup 1.0000x reference)
//
#include <hip/hip_runtime.h>
#include <stdint.h>

#define BATCH 16
#define HW (1024*1024)                 // pixels per batch image
#define NPIX (BATCH * HW)              // 16,777,216 total pixels
#define GRID 1024                      // 4 blocks/CU x 256 CUs -> ALL co-resident
#define TPB 256
#define VPT 16                         // vf4 per thread -> 64 data VGPRs
#define V4B (TPB * VPT)                // 4096 vf4 (64 KB) per block
#define BPB (GRID / BATCH)             // 64 blocks per batch image

typedef float vf4 __attribute__((ext_vector_type(4)));

// ---------------------------------------------------------------------------
// Single plain-launch kernel (graph-capture safe). Per-batch software barrier
// built from device-scope atomics:
//   phase 1: each block scans its 64 KB slice held in registers, publishes a
//            packed {minbin,maxbin,valid} partial, then ACQ_REL fetch_adds a
//            per-batch arrival counter.
//   last arriver (old==63) acquire-sees all 64 partials, wave-reduces them to
//            the batch flag, publishes flag|sentinel with a SYSTEM-scope store
//            (write-through; pollers read the coherence point, so no stale-L2
//            spin hazard and no per-poll L2 invalidates).
//   phase 3: softmax from register-held input, NT-store both planes.
//
// Deadlock-free: __launch_bounds__(256,4) caps VGPR<=128 -> >=4 blocks/CU
// capacity; grid == capacity (1024) so every block is resident before any
// barrier completes. Batches are independent (64-block barriers only).
//
// Flag semantics (harness-verified absmax=0 in earlier rounds):
//   flag = (any pixel with integral mi in [0,255]) && (min occupied histogram
//          bin != max occupied bin).  All |i-k|*hist[k] terms are non-negative
//   integers -> no fp cancellation in the reference matvec, so mask.max()>0
//   iff a second bin is occupied.
//
// m = flag ? (x*255)/255 : 0 ; o0 = 1/(1+e^{1-2m}) ; o1 = e * o0.
// Output layout: [msks0 (16M floats) | msks1 (16M floats)].
// ---------------------------------------------------------------------------
__device__ __forceinline__ float2 softmax2(float x, float fm) {
    float mi = x * 255.0f;
    float m = (mi / 255.0f) * fm;      // fm in {0,1}: masked or zeroed
    float e = expf(1.0f - 2.0f * m);   // e^{b-a}, b-a = (1-m)-m
    float r = 1.0f / (1.0f + e);
    return make_float2(r, e * r);      // (e^a, e^b) / (e^a+e^b)
}

__global__ __launch_bounds__(TPB, 4) void fused_kernel(const float* __restrict__ in,
                                                       unsigned* __restrict__ ctr,      // [16]
                                                       unsigned* __restrict__ flagw,    // [16]
                                                       unsigned long long* __restrict__ partials, // [1024]
                                                       float* __restrict__ out) {
    const int tid = threadIdx.x;
    const int blk = blockIdx.x;
    const int batch = blk >> 6;                          // 64 blocks per batch
    const size_t base = (size_t)blk * V4B + tid;

    // ---- Phase 1: load 16 vf4 into registers (NT: input is never re-read)
    const vf4* src = (const vf4*)in;
    vf4 d[VPT];
#pragma unroll
    for (int j = 0; j < VPT; ++j)
        d[j] = __builtin_nontemporal_load(&src[base + (size_t)j * TPB]);

    int minb = 0x7FFF, maxb = -1, valid = 0;
#pragma unroll
    for (int j = 0; j < VPT; ++j) {
        float v[4] = {d[j].x, d[j].y, d[j].z, d[j].w};
#pragma unroll
        for (int k = 0; k < 4; ++k) {
            float mi = v[k] * 255.0f;                    // replicate reference arithmetic
            if (mi >= 0.0f && mi <= 255.0f) {            // histogram range, edges inclusive
                int b = (int)(mi * (256.0f / 255.0f));
                if (b > 255) b = 255;                    // right edge -> last bin
                minb = min(minb, b);
                maxb = max(maxb, b);
                valid |= (mi == rintf(mi)) ? 1 : 0;      // round-half-even == jnp.round
            }
        }
    }
    // 64-lane butterfly reduce within each wave
#pragma unroll
    for (int off = 32; off > 0; off >>= 1) {
        minb  = min(minb, __shfl_xor(minb, off));
        maxb  = max(maxb, __shfl_xor(maxb, off));
        valid |= __shfl_xor(valid, off);
    }
    // cross-wave reduce via LDS (4 waves)
    __shared__ int sm[4], sx[4], sv[4];
    __shared__ unsigned s_last;
    __shared__ float s_fm;
    const int w = tid >> 6;
    if ((tid & 63) == 0) { sm[w] = minb; sx[w] = maxb; sv[w] = valid; }
    __syncthreads();
    if (tid == 0) {
#pragma unroll
        for (int i = 1; i < 4; ++i) {
            minb  = min(minb, sm[i]);
            maxb  = max(maxb, sx[i]);
            valid |= sv[i];
        }
        // pack: [minb:16 | maxb:16 | valid:32]
        unsigned long long p =
            ((unsigned long long)(unsigned)(((minb & 0xFFFF) << 16) | (maxb & 0xFFFF)) << 32)
            | (unsigned)valid;
        __hip_atomic_store(&partials[blk], p, __ATOMIC_RELAXED, __HIP_MEMORY_SCOPE_AGENT);
        // release (orders the partial store); acquire (if we're last, all 64
        // partials are visible to this block)
        unsigned old = __hip_atomic_fetch_add(&ctr[batch], 1u,
                                              __ATOMIC_ACQ_REL, __HIP_MEMORY_SCOPE_AGENT);
        s_last = (old == BPB - 1) ? 1u : 0u;
    }
    __syncthreads();

    if (s_last) {
        // ---- last block of this batch: wave 0 reduces its 64 partials
        if (tid < 64) {
            unsigned long long p = __hip_atomic_load(&partials[batch * BPB + tid],
                                                     __ATOMIC_RELAXED, __HIP_MEMORY_SCOPE_AGENT);
            int mn = (int)(short)(p >> 48);              // sign-extend: 0x7FFF stays
            int mx = (int)(short)(p >> 32);              //              -1 stays
            unsigned vv = (unsigned)p;
#pragma unroll
            for (int off = 32; off > 0; off >>= 1) {
                mn = min(mn, __shfl_xor(mn, off));
                mx = max(mx, __shfl_xor(mx, off));
                vv |= (unsigned)__shfl_xor((int)vv, off);
            }
            if (tid == 0) {
                unsigned f = (vv && (mn != mx)) ? 3u : 2u;   // bit1 = done, bit0 = flag
                __hip_atomic_store(&flagw[batch], f,
                                   __ATOMIC_RELAXED, __HIP_MEMORY_SCOPE_SYSTEM);
                s_fm = (float)(f & 1u);
            }
        }
    } else if (tid == 0) {
        // ---- poll at SYSTEM scope (reads coherence point: no stale-L2 spin,
        // no L2-invalidate storm). Only the flag VALUE is consumed -> relaxed ok.
        unsigned f;
        for (;;) {
            f = __hip_atomic_load(&flagw[batch], __ATOMIC_RELAXED, __HIP_MEMORY_SCOPE_SYSTEM);
            if (f) break;
            __builtin_amdgcn_s_sleep(2);
        }
        s_fm = (float)(f & 1u);
    }
    __syncthreads();
    const float fm = s_fm;

    // ---- Phase 3: softmax from register-held input, NT-store both planes
    vf4* o0p = (vf4*)out;
    vf4* o1p = (vf4*)(out + (size_t)NPIX);
#pragma unroll
    for (int j = 0; j < VPT; ++j) {
        float2 rx = softmax2(d[j].x, fm);
        float2 ry = softmax2(d[j].y, fm);
        float2 rz = softmax2(d[j].z, fm);
        float2 rw = softmax2(d[j].w, fm);
        vf4 o0 = {rx.x, ry.x, rz.x, rw.x};
        vf4 o1 = {rx.y, ry.y, rz.y, rw.y};
        const size_t idx = base + (size_t)j * TPB;
        __builtin_nontemporal_store(o0, &o0p[idx]);
        __builtin_nontemporal_store(o1, &o1p[idx]);
    }
}

// ---------------------------------------------------------------------------
extern "C" void kernel_launch(void* const* d_in, const int* in_sizes, int n_in,
                              void* d_out, int out_size, void* d_ws, size_t ws_size,
                              hipStream_t stream) {
    const float* irr = (const float*)d_in[0];
    // d_in[1] (image_vis) is unused by the reference's outputs.
    float* out = (float*)d_out;

    // ws layout: [0,64)   ctr[16]     (uint)
    //            [64,128) flagw[16]   (uint)
    //            [256,...) partials[1024] (uint64)
    unsigned* ctr   = (unsigned*)d_ws;
    unsigned* flagw = ctr + 16;
    unsigned long long* partials = (unsigned long long*)((char*)d_ws + 256);

    // counters/flagwords must start at 0 each replay (ws is re-poisoned);
    // partials need no init (fully written before any read).
    hipMemsetAsync(d_ws, 0, 128, stream);

    fused_kernel<<<GRID, TPB, 0, stream>>>(irr, ctr, flagw, partials, out);
}

// Round 4
// 258.412 us; speedup vs baseline: 1.1540x; 1.1540x over previous
//
#include <hip/hip_runtime.h>
#include <stdint.h>

#define BATCH 16
#define HW (1024*1024)                 // pixels per batch image
#define NPIX (BATCH * HW)              // 16,777,216 total pixels
#define NV4 (NPIX / 4)                 // 4,194,304 float4 elements
#define SBLK 64                        // scan blocks per batch
#define SGRID (SBLK * BATCH)           // 1024 scan blocks
#define SV4 4096                       // vf4 per scan block (16/thread)
#define OGRID 2048                     // out blocks
#define OVPT 8                         // vf4 per thread in out kernel
#define OV4B (256 * OVPT)              // 2048 vf4 per out block

typedef float vf4 __attribute__((ext_vector_type(4)));

// ---------------------------------------------------------------------------
// Flag semantics (harness-verified absmax=0 in rounds 0/1/3):
//   flag[b] = (any pixel of image b with integral mi in [0,255])
//             && (min occupied histogram bin != max occupied bin)
// All |i-k|*hist[k] terms are non-negative integers -> no fp cancellation in
// the reference matvec, so mask.max()>0 iff a second bin is occupied.
//
// KEY MONOTONICITY: flag is proven TRUE by ANY subset of pixels containing a
// valid pixel and two distinct occupied bins — more pixels can only grow the
// occupied-bin set and keep valid true. So a block that proves the condition
// on a small prefix publishes a per-batch proof word; other blocks of that
// batch skip their full scan. Full-scan fallback keeps worst-case inputs
// (constant images, no valid pixels) exactly correct.
// ---------------------------------------------------------------------------

__device__ __forceinline__ void accum4(vf4 x, int& minb, int& maxb, int& valid) {
    float v[4] = {x.x, x.y, x.z, x.w};
#pragma unroll
    for (int k = 0; k < 4; ++k) {
        float mi = v[k] * 255.0f;                 // replicate reference arithmetic
        if (mi >= 0.0f && mi <= 255.0f) {         // histogram range, edges inclusive
            int b = (int)(mi * (256.0f / 255.0f));
            if (b > 255) b = 255;                 // right edge -> last bin
            minb = min(minb, b);
            maxb = max(maxb, b);
            valid |= (mi == rintf(mi)) ? 1 : 0;   // round-half-even == jnp.round
        }
    }
}

__device__ __forceinline__ void wave_reduce(int& minb, int& maxb, int& valid) {
#pragma unroll
    for (int off = 32; off > 0; off >>= 1) {
        minb  = min(minb, __shfl_xor(minb, off));
        maxb  = max(maxb, __shfl_xor(maxb, off));
        valid |= __shfl_xor(valid, off);
    }
}

// ---------------------------------------------------------------------------
// Kernel 1: early-proof scan. Prefix (4 KB/block) -> publish/check per-batch
// proof -> full scan only if unproven (with periodic proof rechecks).
// ---------------------------------------------------------------------------
__global__ __launch_bounds__(256) void scan_kernel(const float* __restrict__ in,
                                                   unsigned* __restrict__ proofs,   // [16]
                                                   uint2* __restrict__ partials) {  // [1024]
    const int tid = threadIdx.x;
    const int blk = blockIdx.x;
    const int batch = blk >> 6;
    const vf4* src = (const vf4*)in + (size_t)blk * SV4;

    __shared__ int sm[4], sx[4], sv[4];
    __shared__ int s_proof;
    const int w = tid >> 6;

    // ---- prefix: one vf4 per thread (coalesced, LLC-resident)
    int minb = 0x7FFF, maxb = -1, valid = 0;
    accum4(src[tid], minb, maxb, valid);
    wave_reduce(minb, maxb, valid);
    if ((tid & 63) == 0) { sm[w] = minb; sx[w] = maxb; sv[w] = valid; }
    __syncthreads();
    if (tid == 0) {
        int mn = sm[0], mx = sx[0], vv = sv[0];
#pragma unroll
        for (int i = 1; i < 4; ++i) { mn = min(mn, sm[i]); mx = max(mx, sx[i]); vv |= sv[i]; }
        if (vv && mn != mx) {
            __hip_atomic_store(&proofs[batch], 1u, __ATOMIC_RELAXED, __HIP_MEMORY_SCOPE_AGENT);
            s_proof = 1;
        } else {
            s_proof = (int)__hip_atomic_load(&proofs[batch], __ATOMIC_RELAXED, __HIP_MEMORY_SCOPE_AGENT);
        }
    }
    __syncthreads();
    int skip = s_proof;

    if (!skip) {
        // ---- full scan (includes prefix range again; monotone so harmless)
        minb = 0x7FFF; maxb = -1; valid = 0;
        for (int j = 0; j < 16; ++j) {
            if (j == 4 || j == 8 || j == 12) {          // periodic proof recheck
                __syncthreads();                         // all past previous s_proof read
                if (tid == 0)
                    s_proof = (int)__hip_atomic_load(&proofs[batch], __ATOMIC_RELAXED,
                                                     __HIP_MEMORY_SCOPE_AGENT);
                __syncthreads();
                if (s_proof) { skip = 1; break; }
            }
            accum4(src[tid + j * 256], minb, maxb, valid);
        }
        if (!skip) {
            wave_reduce(minb, maxb, valid);
            if ((tid & 63) == 0) { sm[w] = minb; sx[w] = maxb; sv[w] = valid; }
            __syncthreads();
            if (tid == 0) {
#pragma unroll
                for (int i = 1; i < 4; ++i) {
                    minb  = min(minb, sm[i]);
                    maxb  = max(maxb, sx[i]);
                    valid |= sv[i];
                }
                uint2 p;
                p.x = ((unsigned)(minb & 0xFFFF) << 16) | (unsigned)(maxb & 0xFFFF);
                p.y = (unsigned)valid;
                partials[blk] = p;
            }
        }
    }
    if (skip && tid == 0) {
        // neutral partial: proof forces flag TRUE, partials are then unused,
        // but keep the reduce well-defined.
        partials[blk] = make_uint2(0x7FFFFFFFu, 0u);    // minb=0x7FFF, maxb=-1, valid=0
    }
}

// ---------------------------------------------------------------------------
// Kernel 2: fused flag-reduce + mask-apply + 2-way softmax, 8 vf4/thread.
// m = flag ? (x*255)/255 : 0 ; o0 = 1/(1+e^{1-2m}) ; o1 = e * o0.
// Output layout: [msks0 (16M floats) | msks1 (16M floats)].
// ---------------------------------------------------------------------------
__device__ __forceinline__ float2 softmax2(float x, float fm) {
    float mi = x * 255.0f;
    float m = (mi / 255.0f) * fm;      // fm in {0,1}: masked or zeroed
    float e = expf(1.0f - 2.0f * m);   // e^{b-a}, b-a = (1-m)-m
    float r = 1.0f / (1.0f + e);
    return make_float2(r, e * r);      // (e^a, e^b) / (e^a+e^b)
}

__global__ __launch_bounds__(256) void out_kernel(const float* __restrict__ in,
                                                  const unsigned* __restrict__ proofs,
                                                  const uint2* __restrict__ partials,
                                                  float* __restrict__ out) {
    const int tid = threadIdx.x;
    const int blk = blockIdx.x;
    const int batch = blk >> 7;                    // 128 out-blocks per batch image
    const size_t base = (size_t)blk * OV4B + tid;

    // issue the (LLC-resident) input loads first — latency overlaps the reduce
    const vf4* src = (const vf4*)in;
    vf4 d[OVPT];
#pragma unroll
    for (int j = 0; j < OVPT; ++j)
        d[j] = src[base + (size_t)j * 256];

    __shared__ float s_fm;
    if (tid < 64) {
        uint2 p = partials[batch * SBLK + tid];
        int mn = (int)(short)(p.x >> 16);          // sign-extend: 0x7FFF stays, -1 stays
        int mx = (int)(short)(p.x & 0xFFFF);
        unsigned vv = p.y;
#pragma unroll
        for (int off = 32; off > 0; off >>= 1) {
            mn = min(mn, __shfl_xor(mn, off));
            mx = max(mx, __shfl_xor(mx, off));
            vv |= (unsigned)__shfl_xor((int)vv, off);
        }
        if (tid == 0) {
            unsigned pr = proofs[batch];
            s_fm = (pr || (vv && mn != mx)) ? 1.0f : 0.0f;
        }
    }
    __syncthreads();
    const float fm = s_fm;

    vf4* o0p = (vf4*)out;
    vf4* o1p = (vf4*)(out + (size_t)NPIX);
#pragma unroll
    for (int j = 0; j < OVPT; ++j) {
        float2 rx = softmax2(d[j].x, fm);
        float2 ry = softmax2(d[j].y, fm);
        float2 rz = softmax2(d[j].z, fm);
        float2 rw = softmax2(d[j].w, fm);
        vf4 o0 = {rx.x, ry.x, rz.x, rw.x};
        vf4 o1 = {rx.y, ry.y, rz.y, rw.y};
        const size_t idx = base + (size_t)j * 256;
        __builtin_nontemporal_store(o0, &o0p[idx]);
        __builtin_nontemporal_store(o1, &o1p[idx]);
    }
}

// ---------------------------------------------------------------------------
extern "C" void kernel_launch(void* const* d_in, const int* in_sizes, int n_in,
                              void* d_out, int out_size, void* d_ws, size_t ws_size,
                              hipStream_t stream) {
    const float* irr = (const float*)d_in[0];
    // d_in[1] (image_vis) is unused by the reference's outputs.
    float* out = (float*)d_out;

    // ws layout: [0,64)    proofs[16]     (uint)
    //            [256,...) partials[1024] (uint2)
    unsigned* proofs = (unsigned*)d_ws;
    uint2* partials  = (uint2*)((char*)d_ws + 256);

    // proofs must start at 0 each replay (ws is re-poisoned by the harness);
    // partials are fully written by scan_kernel before any read.
    hipMemsetAsync(d_ws, 0, 64, stream);

    scan_kernel<<<SGRID, 256, 0, stream>>>(irr, proofs, partials);
    out_kernel<<<OGRID, 256, 0, stream>>>(irr, proofs, partials, out);
}

// Round 5
// 255.672 us; speedup vs baseline: 1.1664x; 1.0107x over previous
//
#include <hip/hip_runtime.h>
#include <stdint.h>

#define BATCH 16
#define HW (1024*1024)                 // pixels per batch image
#define NPIX (BATCH * HW)              // 16,777,216 total pixels
#define NV4 (NPIX / 4)                 // 4,194,304 float4 elements
#define SBLK 64                        // scan blocks per batch
#define SGRID (SBLK * BATCH)           // 1024 scan blocks
#define SV4 4096                       // vf4 per scan block (16/thread)

typedef float vf4 __attribute__((ext_vector_type(4)));

// ---------------------------------------------------------------------------
// Flag semantics (harness-verified absmax=0 in rounds 0/1/3/4):
//   flag[b] = (any pixel of image b with integral mi in [0,255])
//             && (min occupied histogram bin != max occupied bin)
// All |i-k|*hist[k] terms are non-negative integers -> no fp cancellation in
// the reference matvec, so mask.max()>0 iff a second bin is occupied.
//
// MONOTONICITY: flag is proven TRUE by ANY pixel subset containing a valid
// pixel and two distinct occupied bins. A block that proves it on a 4 KB
// prefix publishes a per-batch proof word; sibling blocks skip their full
// scan. Full-scan fallback keeps adversarial inputs exactly correct.
// ---------------------------------------------------------------------------

__device__ __forceinline__ void accum4(vf4 x, int& minb, int& maxb, int& valid) {
    float v[4] = {x.x, x.y, x.z, x.w};
#pragma unroll
    for (int k = 0; k < 4; ++k) {
        float mi = v[k] * 255.0f;                 // replicate reference arithmetic
        if (mi >= 0.0f && mi <= 255.0f) {         // histogram range, edges inclusive
            int b = (int)(mi * (256.0f / 255.0f));
            if (b > 255) b = 255;                 // right edge -> last bin
            minb = min(minb, b);
            maxb = max(maxb, b);
            valid |= (mi == rintf(mi)) ? 1 : 0;   // round-half-even == jnp.round
        }
    }
}

__device__ __forceinline__ void wave_reduce(int& minb, int& maxb, int& valid) {
#pragma unroll
    for (int off = 32; off > 0; off >>= 1) {
        minb  = min(minb, __shfl_xor(minb, off));
        maxb  = max(maxb, __shfl_xor(maxb, off));
        valid |= __shfl_xor(valid, off);
    }
}

// ---------------------------------------------------------------------------
// Kernel 1: early-proof scan (verbatim from round 4 — passed correctness).
// Prefix (4 KB/block) -> publish/check per-batch proof -> full scan only if
// unproven (with periodic proof rechecks).
// ---------------------------------------------------------------------------
__global__ __launch_bounds__(256) void scan_kernel(const float* __restrict__ in,
                                                   unsigned* __restrict__ proofs,   // [16]
                                                   uint2* __restrict__ partials) {  // [1024]
    const int tid = threadIdx.x;
    const int blk = blockIdx.x;
    const int batch = blk >> 6;
    const vf4* src = (const vf4*)in + (size_t)blk * SV4;

    __shared__ int sm[4], sx[4], sv[4];
    __shared__ int s_proof;
    const int w = tid >> 6;

    // ---- prefix: one vf4 per thread (coalesced)
    int minb = 0x7FFF, maxb = -1, valid = 0;
    accum4(src[tid], minb, maxb, valid);
    wave_reduce(minb, maxb, valid);
    if ((tid & 63) == 0) { sm[w] = minb; sx[w] = maxb; sv[w] = valid; }
    __syncthreads();
    if (tid == 0) {
        int mn = sm[0], mx = sx[0], vv = sv[0];
#pragma unroll
        for (int i = 1; i < 4; ++i) { mn = min(mn, sm[i]); mx = max(mx, sx[i]); vv |= sv[i]; }
        if (vv && mn != mx) {
            __hip_atomic_store(&proofs[batch], 1u, __ATOMIC_RELAXED, __HIP_MEMORY_SCOPE_AGENT);
            s_proof = 1;
        } else {
            s_proof = (int)__hip_atomic_load(&proofs[batch], __ATOMIC_RELAXED, __HIP_MEMORY_SCOPE_AGENT);
        }
    }
    __syncthreads();
    int skip = s_proof;

    if (!skip) {
        // ---- full scan (includes prefix range again; monotone so harmless)
        minb = 0x7FFF; maxb = -1; valid = 0;
        for (int j = 0; j < 16; ++j) {
            if (j == 4 || j == 8 || j == 12) {          // periodic proof recheck
                __syncthreads();                         // all past previous s_proof read
                if (tid == 0)
                    s_proof = (int)__hip_atomic_load(&proofs[batch], __ATOMIC_RELAXED,
                                                     __HIP_MEMORY_SCOPE_AGENT);
                __syncthreads();
                if (s_proof) { skip = 1; break; }
            }
            accum4(src[tid + j * 256], minb, maxb, valid);
        }
        if (!skip) {
            wave_reduce(minb, maxb, valid);
            if ((tid & 63) == 0) { sm[w] = minb; sx[w] = maxb; sv[w] = valid; }
            __syncthreads();
            if (tid == 0) {
#pragma unroll
                for (int i = 1; i < 4; ++i) {
                    minb  = min(minb, sm[i]);
                    maxb  = max(maxb, sx[i]);
                    valid |= sv[i];
                }
                uint2 p;
                p.x = ((unsigned)(minb & 0xFFFF) << 16) | (unsigned)(maxb & 0xFFFF);
                p.y = (unsigned)valid;
                partials[blk] = p;
            }
        }
    }
    if (skip && tid == 0) {
        // neutral partial: proof forces flag TRUE, partials then unused,
        // but keep the reduce well-defined.
        partials[blk] = make_uint2(0x7FFFFFFFu, 0u);    // minb=0x7FFF, maxb=-1, valid=0
    }
}

// ---------------------------------------------------------------------------
// Kernel 2: R1's proven out_kernel shape (16384 blocks x 1 vf4/thread),
// flag-reduce fused in wave 0, proof word OR'd in.
// m = flag ? (x*255)/255 : 0 ; o0 = 1/(1+e^{1-2m}) ; o1 = e * o0.
// Output layout: [msks0 (16M floats) | msks1 (16M floats)].
// ---------------------------------------------------------------------------
__device__ __forceinline__ float2 softmax2(float x, float fm) {
    float mi = x * 255.0f;
    float m = (mi / 255.0f) * fm;      // fm in {0,1}: masked or zeroed
    float e = expf(1.0f - 2.0f * m);   // e^{b-a}, b-a = (1-m)-m
    float r = 1.0f / (1.0f + e);
    return make_float2(r, e * r);      // (e^a, e^b) / (e^a+e^b)
}

__global__ __launch_bounds__(256) void out_kernel(const float* __restrict__ in,
                                                  const unsigned* __restrict__ proofs,
                                                  const uint2* __restrict__ partials,
                                                  float* __restrict__ out) {
    const int batch = blockIdx.x >> 10;    // 1024 out-blocks per batch image (uniform)
    const size_t i4 = (size_t)blockIdx.x * 256 + threadIdx.x;

    // issue the input load first — latency overlaps the reduce
    vf4 x = ((const vf4*)in)[i4];

    __shared__ float s_fm;
    if (threadIdx.x < 64) {
        uint2 p = partials[batch * SBLK + threadIdx.x];
        int mn = (int)(short)(p.x >> 16);      // sign-extend: 0x7FFF stays, -1 stays
        int mx = (int)(short)(p.x & 0xFFFF);
        unsigned vv = p.y;
#pragma unroll
        for (int off = 32; off > 0; off >>= 1) {
            mn = min(mn, __shfl_xor(mn, off));
            mx = max(mx, __shfl_xor(mx, off));
            vv |= (unsigned)__shfl_xor((int)vv, off);
        }
        if (threadIdx.x == 0) {
            unsigned pr = proofs[batch];
            s_fm = (pr || (vv && mn != mx)) ? 1.0f : 0.0f;
        }
    }
    __syncthreads();
    const float fm = s_fm;

    float2 rx = softmax2(x.x, fm);
    float2 ry = softmax2(x.y, fm);
    float2 rz = softmax2(x.z, fm);
    float2 rw = softmax2(x.w, fm);
    vf4 o0 = {rx.x, ry.x, rz.x, rw.x};
    vf4 o1 = {rx.y, ry.y, rz.y, rw.y};
    __builtin_nontemporal_store(o0, &((vf4*)out)[i4]);
    __builtin_nontemporal_store(o1, &((vf4*)(out + (size_t)NPIX))[i4]);
}

// ---------------------------------------------------------------------------
extern "C" void kernel_launch(void* const* d_in, const int* in_sizes, int n_in,
                              void* d_out, int out_size, void* d_ws, size_t ws_size,
                              hipStream_t stream) {
    const float* irr = (const float*)d_in[0];
    // d_in[1] (image_vis) is unused by the reference's outputs.
    float* out = (float*)d_out;

    // ws layout: [0,64)    proofs[16]     (uint)
    //            [256,...) partials[1024] (uint2)
    unsigned* proofs = (unsigned*)d_ws;
    uint2* partials  = (uint2*)((char*)d_ws + 256);

    // proofs must start at 0 each replay (ws is re-poisoned by the harness);
    // partials are fully written by scan_kernel before any read.
    hipMemsetAsync(d_ws, 0, 64, stream);

    scan_kernel<<<SGRID, 256, 0, stream>>>(irr, proofs, partials);
    out_kernel<<<NV4 / 256, 256, 0, stream>>>(irr, proofs, partials, out);
}

// Round 6
// 224.137 us; speedup vs baseline: 1.3305x; 1.1407x over previous
//
#include <hip/hip_runtime.h>
#include <stdint.h>

#define BATCH 16
#define HW (1024*1024)                 // pixels per batch image
#define NPIX (BATCH * HW)              // 16,777,216 total pixels
#define NV4 (NPIX / 4)                 // 4,194,304 float4 elements
#define SBLK 64                        // scan blocks per batch
#define SGRID (SBLK * BATCH)           // 1024 scan blocks
#define SV4 4096                       // vf4 per scan block (16/thread)
#define OVPT 2                         // vf4 per thread in out kernel
#define OGRID (NV4 / 256 / OVPT)       // 8192 out blocks

typedef float vf4 __attribute__((ext_vector_type(4)));

// ---------------------------------------------------------------------------
// Kernel 1: full-scan streaming reduction (R0/R1 proven structure).
//   minb  = min occupied histogram bin (0x7FFF if none in-range)
//   maxb  = max occupied histogram bin (-1 if none)
//   valid = any pixel with integral mi in [0,255]
// flag = valid && (minb != maxb): for a valid pixel mi=n its bin index
// equals n, and all |i-k|*hist[k] terms are non-negative integers (no fp
// cancellation in the reference matvec), so mask.max()>0 iff a second bin
// is occupied.  (Harness-verified absmax=0 in rounds 0/1/3/4/5.)
//
// Loads are CACHED on purpose: this pure-read phase pays the input's one
// mandatory HBM crossing at full read BW and leaves it LLC-resident for
// out_kernel (mixed cold-read+write in out_kernel measured ~30 µs slower
// in R4/R5).
// ---------------------------------------------------------------------------
__global__ __launch_bounds__(256) void scan_kernel(const float* __restrict__ in,
                                                   uint2* __restrict__ partials) {
    const int tid = threadIdx.x;
    const int blk = blockIdx.x;
    int minb = 0x7FFF, maxb = -1, valid = 0;

    const vf4* src = (const vf4*)in + (size_t)blk * SV4;
    for (int i = tid; i < SV4; i += 256) {
        vf4 x = src[i];                               // cached: warm the LLC for kernel 2
        float v[4] = {x.x, x.y, x.z, x.w};
#pragma unroll
        for (int k = 0; k < 4; ++k) {
            float mi = v[k] * 255.0f;                 // replicate reference arithmetic
            if (mi >= 0.0f && mi <= 255.0f) {         // histogram range, edges inclusive
                int b = (int)(mi * (256.0f / 255.0f));
                if (b > 255) b = 255;                 // right edge -> last bin
                minb = min(minb, b);
                maxb = max(maxb, b);
                valid |= (mi == rintf(mi)) ? 1 : 0;   // round-half-even == jnp.round
            }
        }
    }
    // 64-lane butterfly reduce within each wave
#pragma unroll
    for (int off = 32; off > 0; off >>= 1) {
        minb  = min(minb, __shfl_xor(minb, off));
        maxb  = max(maxb, __shfl_xor(maxb, off));
        valid |= __shfl_xor(valid, off);
    }
    // cross-wave reduce via LDS (4 waves)
    __shared__ int sm[4], sx[4], sv[4];
    const int w = tid >> 6;
    if ((tid & 63) == 0) { sm[w] = minb; sx[w] = maxb; sv[w] = valid; }
    __syncthreads();
    if (tid == 0) {
#pragma unroll
        for (int i = 1; i < 4; ++i) {
            minb  = min(minb, sm[i]);
            maxb  = max(maxb, sx[i]);
            valid |= sv[i];
        }
        uint2 p;
        p.x = ((unsigned)(minb & 0xFFFF) << 16) | (unsigned)(maxb & 0xFFFF);
        p.y = (unsigned)valid;
        partials[blk] = p;
    }
}

// ---------------------------------------------------------------------------
// Kernel 2: fused flag-reduce + mask-apply + 2-way softmax, 2 vf4/thread.
// Wave 0 reduces the batch's 64 partials (L2-hot) while the two independent
// input loads (LLC-resident) are already in flight. Half the blocks of R1
// -> half the per-block flag-reduce and launch/tail overhead.
// m = flag ? (x*255)/255 : 0 ; o0 = 1/(1+e^{1-2m}) ; o1 = e * o0.
// Output layout: [msks0 (16M floats) | msks1 (16M floats)].
// ---------------------------------------------------------------------------
__device__ __forceinline__ float2 softmax2(float x, float fm) {
    float mi = x * 255.0f;
    float m = (mi / 255.0f) * fm;      // fm in {0,1}: masked or zeroed
    float e = expf(1.0f - 2.0f * m);   // e^{b-a}, b-a = (1-m)-m
    float r = 1.0f / (1.0f + e);
    return make_float2(r, e * r);      // (e^a, e^b) / (e^a+e^b)
}

__global__ __launch_bounds__(256) void out_kernel(const float* __restrict__ in,
                                                  const uint2* __restrict__ partials,
                                                  float* __restrict__ out) {
    const int batch = blockIdx.x >> 9;             // 512 out-blocks per batch image
    const size_t base = (size_t)blockIdx.x * (256 * OVPT) + threadIdx.x;

    // issue both (LLC-resident) input loads first — latency overlaps the reduce
    const vf4* src = (const vf4*)in;
    vf4 x0 = src[base];
    vf4 x1 = src[base + 256];

    __shared__ float s_fm;
    if (threadIdx.x < 64) {
        uint2 p = partials[batch * SBLK + threadIdx.x];
        int mn = (int)(short)(p.x >> 16);          // sign-extend: 0x7FFF stays, -1 stays
        int mx = (int)(short)(p.x & 0xFFFF);
        unsigned vv = p.y;
#pragma unroll
        for (int off = 32; off > 0; off >>= 1) {
            mn = min(mn, __shfl_xor(mn, off));
            mx = max(mx, __shfl_xor(mx, off));
            vv |= (unsigned)__shfl_xor((int)vv, off);
        }
        if (threadIdx.x == 0) s_fm = (vv && mn != mx) ? 1.0f : 0.0f;
    }
    __syncthreads();
    const float fm = s_fm;

    vf4* o0p = (vf4*)out;
    vf4* o1p = (vf4*)(out + (size_t)NPIX);
#pragma unroll
    for (int j = 0; j < OVPT; ++j) {
        vf4 x = (j == 0) ? x0 : x1;
        float2 rx = softmax2(x.x, fm);
        float2 ry = softmax2(x.y, fm);
        float2 rz = softmax2(x.z, fm);
        float2 rw = softmax2(x.w, fm);
        vf4 o0 = {rx.x, ry.x, rz.x, rw.x};
        vf4 o1 = {rx.y, ry.y, rz.y, rw.y};
        const size_t idx = base + (size_t)j * 256;
        __builtin_nontemporal_store(o0, &o0p[idx]);
        __builtin_nontemporal_store(o1, &o1p[idx]);
    }
}

// ---------------------------------------------------------------------------
extern "C" void kernel_launch(void* const* d_in, const int* in_sizes, int n_in,
                              void* d_out, int out_size, void* d_ws, size_t ws_size,
                              hipStream_t stream) {
    const float* irr = (const float*)d_in[0];
    // d_in[1] (image_vis) is unused by the reference's outputs.
    float* out = (float*)d_out;

    uint2* partials = (uint2*)d_ws;                      // 1024 uint2 = 8 KB
    // No memset needed: partials fully written by scan_kernel before any read.

    scan_kernel<<<SGRID, 256, 0, stream>>>(irr, partials);
    out_kernel<<<OGRID, 256, 0, stream>>>(irr, partials, out);
}